// Round 9
// baseline (391.081 us; speedup 1.0000x reference)
//
#include <hip/hip_runtime.h>
#include <hip/hip_bf16.h>

// Round 15: r11 graph/attn EXACTLY (333us best). One change: the TM=128
// gemm path (fat<8>, used only by L1) goes 2-deep -> 3-deep pipeline:
//   stage(t+2); s_waitcnt vmcnt(2*NLD)  -> two full step-times of slack
//   cover the ~600-900cy load latency that 2-deep left exposed (r13 null
//   proved serial-depth isn't L1's binder; latency-per-step is).
// LDS 64->96KB (1 block/CU) for fat<8>; fat<4> launches unchanged (2-deep).
//   L0 {wt-all + cvt}
//   L1 {pool1-fused(K=4096) + qkv/lift/q gemms}   <- 3-deep
//   L2 {fselfA-attn + sself-attn || pool2 + fcrossKV}
//   L3 {fselfB-attn + fcross-attn || scrossKV}
//   L4 {scross-attn || out-proj fself/fcross/sself}
//   L5 {out-proj scross}

typedef __attribute__((ext_vector_type(8))) short bf16x8;
typedef __attribute__((ext_vector_type(4))) float f32x4;
typedef unsigned short u16;
typedef unsigned int u32;

__device__ inline u16 f2bf(float f) {
    __hip_bfloat16 h = __float2bfloat16(f);
    return *reinterpret_cast<u16*>(&h);
}
__device__ inline u32 pack2(float a, float b) {
    return (u32)f2bf(a) | ((u32)f2bf(b) << 16);
}
__device__ inline float bf2f(u16 h) {
    u32 x = ((u32)h) << 16; float f;
    __builtin_memcpy(&f, &x, 4);
    return f;
}
__device__ inline void gld16(const u16* g, u16* l) {
    __builtin_amdgcn_global_load_lds(
        (const __attribute__((address_space(1))) void*)(g),
        (__attribute__((address_space(3))) void*)(l), 16, 0, 0);
}
template <int N>
__device__ inline void wait_vmcnt() {
    if constexpr (N == 0)       asm volatile("s_waitcnt vmcnt(0)" ::: "memory");
    else if constexpr (N == 4)  asm volatile("s_waitcnt vmcnt(4)" ::: "memory");
    else if constexpr (N == 8)  asm volatile("s_waitcnt vmcnt(8)" ::: "memory");
    else if constexpr (N == 16) asm volatile("s_waitcnt vmcnt(16)" ::: "memory");
}

// ---------------- descriptors ----------------
struct GDesc {
    const u16* A; const u16* Bt; const float* bias;
    void* out0; u16* aux0; u16* aux1;
    int lda, ldb, ldc, K, ntx, mode, rshift, tile_end;
};
struct GPack { int n; int pad[3]; GDesc d[8]; };

struct ADesc { const u16* Q; const u16* K; const u16* Vt; u16* O; int Rq, nk, tile_end, q0b; };
struct APack { int n; int pad[3]; ADesc d[2]; };

struct WDesc { const float* src; u16* dst; int ldn, K, tx_, tile_end; };
struct WPack { int n; int pad[3]; WDesc d[12]; };

struct CvtA { const float* a; u16* da; int na8; const float* b; u16* db; };

// ---------------- gemm path ----------------
// modes: 0 fp32+bias | 1 bf16+bias | 2 gelu+bf16 | 3 qkv split | 4 kv split
//        5 bf16 partial (no bias) | 6 bf16+bias causal-shifted rows
// LDS rows are 64 u16 (128 B), chunk-swizzled: LDS[R][c] = glob[R][c^(R&7)].
template <int TMT>
__device__ __forceinline__ void gemm_body(const GPack& pk, int bid, u16* smem)
{
    constexpr int TM = TMT * 16;
    constexpr int W = TMT / 2;
    constexpr int BUF = TM * 64;           // u16 per buffer per operand
    constexpr int NLD = TM / 32 * 2;       // gld_lds per wave per stage
    constexpr int DEPTH = (TMT == 8) ? 3 : 2;
    u16* As = smem;
    u16* Bs = smem + DEPTH * BUF;

    int di = 0;
    while (bid >= pk.d[di].tile_end) ++di;
    const GDesc g = pk.d[di];
    const int base = di ? pk.d[di - 1].tile_end : 0;
    const int local = bid - base;

    // XCD-strip + 4x4-superblock tile order (total%8==0, nty%4==0).
    const int total = g.tile_end - base;
    const int tpx = total >> 3;
    const int T = (local & 7) * tpx + (local >> 3);
    const int tx = (T >> 2) % g.ntx;
    const int ty = ((T / (g.ntx << 2)) << 2) + (T & 3);
    const int row0 = ty * TM, col0 = tx * TM;

    const int t = threadIdx.x;
    const int wave = t >> 6, lane = t & 63;
    const int l15 = lane & 15, quad = lane >> 4;
    const int wm = (wave >> 1) * W * 16, wn = (wave & 1) * W * 16;

    const int srow = wave * 8 + (lane >> 3);
    const int ssw = (((lane & 7) ^ (lane >> 3))) * 8;
    const u16* Ag = g.A + (long long)(row0 + srow) * g.lda + ssw;
    const u16* Bg = g.Bt + (long long)(col0 + srow) * g.ldb + ssw;

    const int c0 = (quad ^ (l15 & 7)) * 8;

    f32x4 acc[W][W];
#pragma unroll
    for (int i = 0; i < W; ++i)
#pragma unroll
        for (int j = 0; j < W; ++j) {
            acc[i][j][0] = 0.f; acc[i][j][1] = 0.f;
            acc[i][j][2] = 0.f; acc[i][j][3] = 0.f;
        }

    auto stage = [&](int buf, int k0) {
#pragma unroll
        for (int r = 0; r < TM / 32; ++r) {
            gld16(Ag + (long long)r * 32 * g.lda + k0, As + buf * BUF + r * 2048 + wave * 512);
            gld16(Bg + (long long)r * 32 * g.ldb + k0, Bs + buf * BUF + r * 2048 + wave * 512);
        }
    };
    auto compute = [&](int buf) {
        const u16* Ab = As + buf * BUF;
        const u16* Bb = Bs + buf * BUF;
#pragma unroll
        for (int kc = 0; kc < 2; ++kc) {
            const int cc = kc ? (c0 ^ 32) : c0;
            bf16x8 af[W], bfr[W];
#pragma unroll
            for (int i = 0; i < W; ++i) {
                af[i]  = *(const bf16x8*)(Ab + (wm + i * 16 + l15) * 64 + cc);
                bfr[i] = *(const bf16x8*)(Bb + (wn + i * 16 + l15) * 64 + cc);
            }
#pragma unroll
            for (int i = 0; i < W; ++i)
#pragma unroll
                for (int j = 0; j < W; ++j)
                    acc[i][j] = __builtin_amdgcn_mfma_f32_16x16x32_bf16(af[i], bfr[j], acc[i][j], 0, 0, 0);
        }
    };

    // counted-vmcnt DEPTH-deep pipeline: loads for tile t+DEPTH-1 issued
    // while computing tile t; the wait targets loads issued DEPTH-1 iters
    // ago (slack = (DEPTH-1) x step-time covers the load latency).
    const int nt = g.K >> 6;
    stage(0, 0);
    if (DEPTH == 3 && nt > 1) stage(1, 64);
    for (int tt = 0; tt < nt; ++tt) {
        const int ahead = tt + DEPTH - 1;
        if (ahead < nt) {
            stage(ahead % DEPTH, ahead << 6);
            wait_vmcnt<(DEPTH - 1) * NLD>();
        } else if (DEPTH == 3 && tt + 1 < nt) {
            wait_vmcnt<NLD>();
        } else {
            wait_vmcnt<0>();
        }
        __builtin_amdgcn_sched_barrier(0);
        __builtin_amdgcn_s_barrier();      // tile-tt data published to all
        __builtin_amdgcn_sched_barrier(0);
        compute(tt % DEPTH);
        __builtin_amdgcn_sched_barrier(0);
        __builtin_amdgcn_s_barrier();      // readers of buf tt%DEPTH done
    }

    const int rmask = (1 << g.rshift) - 1;
#pragma unroll
    for (int i = 0; i < W; ++i)
#pragma unroll
        for (int j = 0; j < W; ++j)
#pragma unroll
            for (int r = 0; r < 4; ++r) {
                int m = row0 + wm + i * 16 + quad * 4 + r;
                int n = col0 + wn + j * 16 + l15;
                float v = acc[i][j][r];
                if (g.mode != 5) v += g.bias[n];
                if (g.mode == 0) {
                    ((float*)g.out0)[(long long)m * g.ldc + n] = v;
                } else if (g.mode == 1 || g.mode == 5) {
                    ((u16*)g.out0)[(long long)m * g.ldc + n] = f2bf(v);
                } else if (g.mode == 2) {
                    float x3 = v * v * v;
                    v = 0.5f * v * (1.f + tanhf(0.7978845608028654f * (v + 0.044715f * x3)));
                    ((u16*)g.out0)[(long long)m * g.ldc + n] = f2bf(v);
                } else if (g.mode == 3) {
                    u16 h = f2bf(v);
                    if (n < 512) ((u16*)g.out0)[(long long)m * 512 + n] = h;
                    else if (n < 1024) g.aux0[(long long)m * 512 + (n - 512)] = h;
                    else {
                        int d = n - 1024;
                        int bb = m >> g.rshift, rr = m & rmask;
                        g.aux1[((long long)((bb * 8 + (d >> 6)) * 64 + (d & 63)) << g.rshift) + rr] = h;
                    }
                } else if (g.mode == 4) {
                    u16 h = f2bf(v);
                    if (n < 512) ((u16*)g.out0)[(long long)m * 512 + n] = h;
                    else {
                        int d = n - 512;
                        int bb = m >> g.rshift, rr = m & rmask;
                        g.aux1[((long long)((bb * 8 + (d >> 6)) * 64 + (d & 63)) << g.rshift) + rr] = h;
                    }
                } else {  // mode 6: causal shift fused
                    int t9 = m & 511;
                    if (t9 != 511) ((u16*)g.out0)[(long long)(m + 1) * g.ldc + n] = f2bf(v);
                    if (t9 == 0)  ((u16*)g.out0)[(long long)m * g.ldc + n] = 0;
                }
            }
}

// ---------------- attention path (r11: QBLK=64, Qs in LDS) ----------------
#define ALD 72

__device__ __forceinline__ void attn_body(const APack& pk, int bid, u16* smem, float prescale)
{
    // LDS carve (u16 units): Qs 4096 | Ks 2x4096 | Vts 2x4096 | Ps 4x16xALD
    u16* Qs  = smem;
    u16* Ks  = smem + 4096;
    u16* Vts = smem + 12288;
    u16* Psb = smem + 20480;

    int di = 0;
    while (bid >= pk.d[di].tile_end) ++di;
    const ADesc g = pk.d[di];
    const int base = di ? pk.d[di - 1].tile_end : 0;
    const int local = bid - base;

    const int t = threadIdx.x;
    const int wave = t >> 6, lane = t & 63;
    const int l15 = lane & 15, quad = lane >> 4;
    const int bh = local & 15, b = bh >> 3, h = bh & 7;
    const int q0 = g.q0b + (local >> 4) * 64;
    const int nk = g.nk;

    const int srow = wave * 8 + (lane >> 3);
    const int ssw = (((lane & 7) ^ (lane >> 3))) * 8;
    const int c0 = (quad ^ (l15 & 7)) * 8;

    const u16* Qg = g.Q + ((long long)(b * g.Rq + q0 + srow) << 9) + h * 64 + ssw;
    const u16* Kg = g.K + ((long long)(b * nk + srow) << 9) + h * 64 + ssw;
    const u16* Vg = g.Vt + (long long)bh * 64 * nk + (long long)srow * nk + ssw;

    auto stage = [&](int buf, int kt) {
#pragma unroll
        for (int r = 0; r < 2; ++r) {
            gld16(Kg + ((long long)(kt + r * 32) << 9), Ks + buf * 4096 + r * 2048 + wave * 512);
            gld16(Vg + (long long)r * 32 * nk + kt, Vts + buf * 4096 + r * 2048 + wave * 512);
        }
    };

    // prologue: Q (2 loads) then K/V tile 0 (4 loads)
#pragma unroll
    for (int r = 0; r < 2; ++r)
        gld16(Qg + ((long long)r * 32 << 9), Qs + r * 2048 + wave * 512);
    stage(0, 0);
    wait_vmcnt<4>();                    // Q landed (tile-0 loads still flying)
    __builtin_amdgcn_sched_barrier(0);
    __builtin_amdgcn_s_barrier();
    __builtin_amdgcn_sched_barrier(0);

    bf16x8 qf[2];
    qf[0] = *(const bf16x8*)(Qs + (wave * 16 + l15) * 64 + c0);
    qf[1] = *(const bf16x8*)(Qs + (wave * 16 + l15) * 64 + (c0 ^ 32));

    f32x4 Oacc[4];
#pragma unroll
    for (int nt2 = 0; nt2 < 4; ++nt2) { Oacc[nt2][0] = 0.f; Oacc[nt2][1] = 0.f; Oacc[nt2][2] = 0.f; Oacc[nt2][3] = 0.f; }
    float lr[4] = {0.f, 0.f, 0.f, 0.f};

    u16* Pw = Psb + wave * 16 * ALD;

    auto acompute = [&](int buf) {
        const u16* Kb = Ks + buf * 4096;
        const u16* Vb = Vts + buf * 4096;
#pragma unroll
        for (int k16 = 0; k16 < 4; ++k16) {
            f32x4 s;
            s[0] = 0.f; s[1] = 0.f; s[2] = 0.f; s[3] = 0.f;
            bf16x8 kf0 = *(const bf16x8*)(Kb + (k16 * 16 + l15) * 64 + c0);
            bf16x8 kf1 = *(const bf16x8*)(Kb + (k16 * 16 + l15) * 64 + (c0 ^ 32));
            __builtin_amdgcn_s_setprio(1);
            s = __builtin_amdgcn_mfma_f32_16x16x32_bf16(qf[0], kf0, s, 0, 0, 0);
            s = __builtin_amdgcn_mfma_f32_16x16x32_bf16(qf[1], kf1, s, 0, 0, 0);
            __builtin_amdgcn_s_setprio(0);
#pragma unroll
            for (int r = 0; r < 4; ++r) {
                float p = exp2f(s[r] * prescale);
                lr[r] += p;
                Pw[(quad * 4 + r) * ALD + k16 * 16 + l15] = f2bf(p);
            }
        }
        bf16x8 pf0 = *(const bf16x8*)(Pw + l15 * ALD + quad * 8);
        bf16x8 pf1 = *(const bf16x8*)(Pw + l15 * ALD + 32 + quad * 8);
        __builtin_amdgcn_s_setprio(1);
#pragma unroll
        for (int nt2 = 0; nt2 < 4; ++nt2) {
            bf16x8 vf0 = *(const bf16x8*)(Vb + (nt2 * 16 + l15) * 64 + c0);
            bf16x8 vf1 = *(const bf16x8*)(Vb + (nt2 * 16 + l15) * 64 + (c0 ^ 32));
            Oacc[nt2] = __builtin_amdgcn_mfma_f32_16x16x32_bf16(pf0, vf0, Oacc[nt2], 0, 0, 0);
            Oacc[nt2] = __builtin_amdgcn_mfma_f32_16x16x32_bf16(pf1, vf1, Oacc[nt2], 0, 0, 0);
        }
        __builtin_amdgcn_s_setprio(0);
    };

    const int nt = nk >> 6;
    for (int tt = 0; tt < nt; ++tt) {
        const int cur = tt & 1;
        if (tt + 1 < nt) {
            stage(cur ^ 1, (tt + 1) << 6);
            wait_vmcnt<4>();
        } else {
            wait_vmcnt<0>();
        }
        __builtin_amdgcn_sched_barrier(0);
        __builtin_amdgcn_s_barrier();
        __builtin_amdgcn_sched_barrier(0);
        acompute(cur);
        __builtin_amdgcn_sched_barrier(0);
        __builtin_amdgcn_s_barrier();
    }

    float inv[4];
#pragma unroll
    for (int r = 0; r < 4; ++r) {
        float s = lr[r];
#pragma unroll
        for (int off = 1; off < 16; off <<= 1) s += __shfl_xor(s, off);
        inv[r] = 1.f / s;
    }

    u16* Ob = g.O + ((long long)(b * g.Rq + q0 + wave * 16 + quad * 4) << 9) + h * 64;
#pragma unroll
    for (int nt2 = 0; nt2 < 4; ++nt2)
#pragma unroll
        for (int r = 0; r < 4; ++r)
            Ob[(long long)r * 512 + nt2 * 16 + l15] = f2bf(Oacc[nt2][r] * inv[r]);
}

// ---------------- weight transpose path ----------------
__device__ __forceinline__ void wt_body(const WPack& pk, int bid, u16* smem)
{
    float* T = (float*)smem;           // [64][68]
    int di = 0;
    while (bid >= pk.d[di].tile_end) ++di;
    const WDesc g = pk.d[di];
    const int base = di ? pk.d[di - 1].tile_end : 0;
    const int local = bid - base;
    const int k0 = (local % g.tx_) * 64;
    const int n0 = (local / g.tx_) * 64;
    const int t = threadIdx.x;
#pragma unroll
    for (int i = 0; i < 4; ++i) {
        int idx = t + i * 256;
        int r = idx >> 4, c4 = idx & 15;
        float4 v = *(const float4*)(g.src + (long long)(k0 + r) * g.ldn + n0 + c4 * 4);
        T[r * 68 + c4 * 4 + 0] = v.x; T[r * 68 + c4 * 4 + 1] = v.y;
        T[r * 68 + c4 * 4 + 2] = v.z; T[r * 68 + c4 * 4 + 3] = v.w;
    }
    __syncthreads();
#pragma unroll
    for (int i = 0; i < 4; ++i) {
        int idx = t + i * 256;
        int rn = idx >> 4, k4 = idx & 15;
        uint2 u;
        u.x = pack2(T[(k4 * 4 + 0) * 68 + rn], T[(k4 * 4 + 1) * 68 + rn]);
        u.y = pack2(T[(k4 * 4 + 2) * 68 + rn], T[(k4 * 4 + 3) * 68 + rn]);
        *(uint2*)(g.dst + (long long)(n0 + rn) * g.K + k0 + k4 * 4) = u;
    }
}

// ---------------- cvt path ----------------
__device__ __forceinline__ void cvt_body(const CvtA& cv, int bid)
{
    int i = bid * 256 + threadIdx.x;
    const float* s; u16* d;
    if (i < cv.na8) { s = cv.a + (long long)i * 8; d = cv.da + (long long)i * 8; }
    else { s = cv.b + (long long)(i - cv.na8) * 8; d = cv.db + (long long)(i - cv.na8) * 8; }
    float4 x = *(const float4*)s;
    float4 y = *(const float4*)(s + 4);
    uint4 u;
    u.x = pack2(x.x, x.y); u.y = pack2(x.z, x.w);
    u.z = pack2(y.x, y.y); u.w = pack2(y.z, y.w);
    *(uint4*)d = u;
}

// ---------------- fat dispatcher ----------------
template <int TMT>
__global__ __launch_bounds__(256)
void fat_multi(APack ap, GPack gp, WPack wp, CvtA cv,
               int na, int ngm, int nwt, float prescale)
{
    constexpr int DEPTH = (TMT == 8) ? 3 : 2;
    constexpr int GB = DEPTH * (TMT * 16 * 64 * 2) * 2;   // gemm LDS bytes
    constexpr int SB = (GB > 50176) ? GB : 50176;         // union with attn/wt
    __shared__ __align__(16) u16 smem[SB / 2];
    int bid = blockIdx.x;
    if (bid < na) { attn_body(ap, bid, smem, prescale); return; }
    bid -= na;
    if (bid < ngm) { gemm_body<TMT>(gp, bid, smem); return; }
    bid -= ngm;
    if (bid < nwt) { wt_body(wp, bid, smem); return; }
    cvt_body(cv, bid - nwt);
}

// ---------------- launch ----------------
extern "C" void kernel_launch(void* const* d_in, const int* in_sizes, int n_in,
                              void* d_out, int out_size, void* d_ws, size_t ws_size,
                              hipStream_t stream)
{
    const float* x_fast      = (const float*)d_in[0];
    const float* x_slow      = (const float*)d_in[1];
    const float* fself_wqkv  = (const float*)d_in[2];
    const float* fself_bqkv  = (const float*)d_in[3];
    const float* fself_wo    = (const float*)d_in[4];
    const float* fself_bo    = (const float*)d_in[5];
    const float* fcross_wqkv = (const float*)d_in[6];
    const float* fcross_bqkv = (const float*)d_in[7];
    const float* fcross_wo   = (const float*)d_in[8];
    const float* fcross_bo   = (const float*)d_in[9];
    const float* sself_wqkv  = (const float*)d_in[10];
    const float* sself_bqkv  = (const float*)d_in[11];
    const float* sself_wo    = (const float*)d_in[12];
    const float* sself_bo    = (const float*)d_in[13];
    const float* scross_wqkv = (const float*)d_in[14];
    const float* scross_bqkv = (const float*)d_in[15];
    const float* scross_wo   = (const float*)d_in[16];
    const float* scross_bo   = (const float*)d_in[17];
    const float* lift_w      = (const float*)d_in[18];
    const float* lift_b      = (const float*)d_in[19];
    const float* pool_w1     = (const float*)d_in[20];
    const float* pool_b1     = (const float*)d_in[21];
    const float* pool_w2     = (const float*)d_in[22];
    const float* pool_b2     = (const float*)d_in[23];

    float* out = (float*)d_out;
    float* zf = out;                       // (2,2048,1024) fp32
    float* zs = out + 2LL * 2048 * 1024;   // (2,512,1024) fp32

    float* ws = (float*)d_ws;
    // ---- ws arena (fl offsets) ----
    u16* pw1T     = (u16*)(ws + 0);          // 4,194,304 fl (dead after L1)
    u16* wqkvT_f  = (u16*)(ws + 4194304);
    u16* wqkvT_c  = (u16*)(ws + 4587520);
    u16* wqkvT_s  = (u16*)(ws + 4980736);
    u16* wqkvT_sc = (u16*)(ws + 5373952);
    u16* liftT    = (u16*)(ws + 5767168);
    u16* pw2T     = (u16*)(ws + 6029312);
    u16* woT_f    = (u16*)(ws + 6553600);
    u16* woT_c    = (u16*)(ws + 6684672);
    u16* woT_s    = (u16*)(ws + 6815744);
    u16* woT_sc   = (u16*)(ws + 6946816);
    u16* xfb      = (u16*)(ws + 7077888);    // 2,097,152 fl (dead after L1)
    u16* xsb      = (u16*)(ws + 9175040);
    u16* q1       = (u16*)(ws + 9699328);    // 1,048,576 fl each
    u16* k1       = (u16*)(ws + 10747904);
    u16* vt1      = (u16*)(ws + 11796480);
    u16* qs       = (u16*)(ws + 12845056);   // 262,144 fl each
    u16* ks       = (u16*)(ws + 13107200);
    u16* vts      = (u16*)(ws + 13369344);
    u16* qcs      = (u16*)(ws + 13631488);   // ends 13,893,632
    // reuse of dead pw1T region after L2 starts (k2/vt2 written in L2):
    u16* k2    = (u16*)(ws + 0);
    u16* vt2   = (u16*)(ws + 262144);
    u16* sbufS = (u16*)(ws + 524288);
    u16* kcs   = (u16*)(ws + 786432);
    u16* vtcs  = (u16*)(ws + 1048576);
    u16* fo1   = (u16*)(ws + 1310720);       // 1,048,576 fl
    u16* fo2   = (u16*)(ws + 2359296);
    u16* so1   = (u16*)(ws + 3407872);
    u16* so2   = (u16*)(ws + 3670016);       // ends 3,932,160
    // d_out zf region as scratch (dead before L4 writes zf):
    u16* q2   = (u16*)(out + 0);             // 1,048,576 fl (dead after L3)
    u16* ybuf = (u16*)(out + 1048576);       // 262,144 fl  (dead after L2)
    u16* hbuf = (u16*)(out + 1310720);       // 1,048,576 fl (gelu(pool1) bf16)

    const float PRESCALE = 0.125f * 1.4426950408889634f;
    APack a_null{}; GPack g_null{}; WPack w_null{}; CvtA cv_null{};

    auto gl = [&](GPack& p, int i, const u16* A, int lda,
                  const u16* Bt, int ldb, const float* bias,
                  void* out0, int ldc, int M, int N, int K, int mode,
                  u16* aux0, u16* aux1, int rshift, int TM, int& te) {
        te += (M / TM) * (N / TM);
        p.d[i] = GDesc{A, Bt, bias, out0, aux0, aux1,
                       lda, ldb, ldc, K, N / TM, mode, rshift, te};
    };

    // ---- L0: ALL weight transposes + cvt ----
    {
        WPack wp; wp.n = 11; int te = 0, i = 0;
        auto add = [&](const float* s, u16* d, int ldn, int K, int N) {
            te += (K / 64) * (N / 64);
            wp.d[i++] = WDesc{s, d, ldn, K, K / 64, te};
        };
        add(pool_w1, pw1T, 2048, 4096, 2048);
        add(fself_wqkv, wqkvT_f, 1536, 512, 1536);
        add(fcross_wqkv, wqkvT_c, 1536, 512, 1536);
        add(sself_wqkv, wqkvT_s, 1536, 512, 1536);
        add(scross_wqkv, wqkvT_sc, 1536, 512, 1536);
        add(lift_w, liftT, 512, 1024, 512);
        add(pool_w2, pw2T, 512, 2048, 512);
        add(fself_wo, woT_f, 512, 512, 512);
        add(fcross_wo, woT_c, 512, 512, 512);
        add(sself_wo, woT_s, 512, 512, 512);
        add(scross_wo, woT_sc, 512, 512, 512);
        CvtA cv{x_fast, xfb, 524288, x_slow, xsb};
        hipLaunchKernelGGL(fat_multi<4>, dim3(te + 2560), dim3(256), 0, stream,
                           a_null, g_null, wp, cv, 0, 0, te, PRESCALE);
    }

    // ---- L1: input-side GEMMs (pool1 fused-gelu, full K; 3-deep pipe) ----
    {
        GPack p; p.n = 6; int te = 0;
        gl(p, 0, xfb, 4096, pw1T, 4096, pool_b1, hbuf, 2048,
           1024, 2048, 4096, 2, 0, 0, 0, 128, te);                    // pool1+gelu
        gl(p, 1, xfb, 1024, wqkvT_f, 512, fself_bqkv, q1, 512,
           4096, 1536, 512, 3, k1, vt1, 11, 128, te);                 // fself qkv
        gl(p, 2, xfb + 512, 1024, wqkvT_c, 512, fcross_bqkv, q2, 512,
           4096, 512, 512, 1, 0, 0, 0, 128, te);                      // fcross q
        gl(p, 3, xsb, 1024, wqkvT_s, 512, sself_bqkv, qs, 512,
           1024, 1536, 512, 3, ks, vts, 9, 128, te);                  // sself qkv
        gl(p, 4, xsb, 1024, liftT, 1024, lift_b, ybuf, 512,
           1024, 512, 1024, 1, 0, 0, 0, 128, te);                     // lift
        gl(p, 5, xsb + 512, 1024, wqkvT_sc, 512, scross_bqkv, qcs, 512,
           1024, 512, 512, 1, 0, 0, 0, 128, te);                      // scross q
        hipLaunchKernelGGL(fat_multi<8>, dim3(te), dim3(256), 0, stream,
                           a_null, p, w_null, cv_null, 0, te, 0, PRESCALE);
    }

    // ---- L2: fselfA-attn + sself-attn || {pool2, fcrossKV} ----
    {
        APack ap; ap.n = 2;
        ap.d[0] = ADesc{q1, k1, vt1, fo1, 2048, 2048, 256, 0};     // fself rows 0..1023
        ap.d[1] = ADesc{qs, ks, vts, so1, 512, 512, 384, 0};       // sself
        GPack p; p.n = 2; int te = 0;
        gl(p, 0, hbuf, 2048, pw2T, 2048, pool_b2, sbufS, 512,
           1024, 512, 2048, 6, 0, 0, 0, 64, te);                   // pool2 (shift)
        gl(p, 1, ybuf, 512, wqkvT_c + 512 * 512, 512, fcross_bqkv + 512, k2, 512,
           1024, 1024, 512, 4, 0, vt2, 9, 64, te);                 // fcross kv
        hipLaunchKernelGGL(fat_multi<4>, dim3(384 + te), dim3(256), 0, stream,
                           ap, p, w_null, cv_null, 384, te, 0, PRESCALE);
    }

    // ---- L3: fselfB-attn + fcross-attn || scrossKV ----
    {
        APack ap; ap.n = 2;
        ap.d[0] = ADesc{q1, k1, vt1, fo1, 2048, 2048, 256, 1024};  // fself rows 1024..2047
        ap.d[1] = ADesc{q2, k2, vt2, fo2, 2048, 512, 768, 0};      // fcross
        GPack p; p.n = 1; int te = 0;
        gl(p, 0, sbufS, 512, wqkvT_sc + 512 * 512, 512, scross_bqkv + 512, kcs, 512,
           1024, 1024, 512, 4, 0, vtcs, 9, 64, te);                // scross kv
        hipLaunchKernelGGL(fat_multi<4>, dim3(768 + te), dim3(256), 0, stream,
                           ap, p, w_null, cv_null, 768, te, 0, PRESCALE);
    }

    // ---- L4: scross-attn || out-proj {fself, fcross, sself} (TM=64) ----
    {
        APack ap; ap.n = 1;
        ap.d[0] = ADesc{qcs, kcs, vtcs, so2, 512, 512, 128, 0};    // scross
        GPack p; p.n = 3; int te = 0;
        gl(p, 0, fo1, 512, woT_f, 512, fself_bo, zf, 1024,
           4096, 512, 512, 0, 0, 0, 0, 64, te);
        gl(p, 1, fo2, 512, woT_c, 512, fcross_bo, zf + 512, 1024,
           4096, 512, 512, 0, 0, 0, 0, 64, te);
        gl(p, 2, so1, 512, woT_s, 512, sself_bo, zs, 1024,
           1024, 512, 512, 0, 0, 0, 0, 64, te);
        hipLaunchKernelGGL(fat_multi<4>, dim3(128 + te), dim3(256), 0, stream,
                           ap, p, w_null, cv_null, 128, te, 0, PRESCALE);
    }

    // ---- L5: out-proj scross (TM=64) ----
    {
        GPack p; p.n = 1; int te = 0;
        gl(p, 0, so2, 512, woT_sc, 512, scross_bo, zs + 512, 1024,
           1024, 512, 512, 0, 0, 0, 0, 64, te);
        hipLaunchKernelGGL(fat_multi<4>, dim3(te), dim3(256), 0, stream,
                           a_null, p, w_null, cv_null, 0, te, 0, PRESCALE);
    }
}

// Round 10
// 374.852 us; speedup vs baseline: 1.0433x; 1.0433x over previous
//
#include <hip/hip_runtime.h>
#include <hip/hip_bf16.h>

// Round 16: r11 graph/attn EXACTLY (333us best). One change: TM=128 gemm
// path (fat<8>, L1 only) switches BK 64->32. LDS 64KB->32KB -> 4-5
// blocks/CU (r15 proved dur ~ 1/(blocks/CU); r13 proved serial depth is
// not the binder, so doubled step count is near-free). 2-deep counted
// vmcnt unchanged. BK=32 swizzle: store LDS[r][c^((r>>1)&3)] via linear
// gld16 dest + pre-swizzled global src; read cc=(quad^((l15>>1)&3))*8.
//   L0 {wt-all + cvt}
//   L1 {pool1-fused(K=4096) + qkv/lift/q gemms}   <- BK=32, 32KB LDS
//   L2 {fselfA-attn + sself-attn || pool2 + fcrossKV}
//   L3 {fselfB-attn + fcross-attn || scrossKV}
//   L4 {scross-attn || out-proj fself/fcross/sself}
//   L5 {out-proj scross}

typedef __attribute__((ext_vector_type(8))) short bf16x8;
typedef __attribute__((ext_vector_type(4))) float f32x4;
typedef unsigned short u16;
typedef unsigned int u32;

__device__ inline u16 f2bf(float f) {
    __hip_bfloat16 h = __float2bfloat16(f);
    return *reinterpret_cast<u16*>(&h);
}
__device__ inline u32 pack2(float a, float b) {
    return (u32)f2bf(a) | ((u32)f2bf(b) << 16);
}
__device__ inline float bf2f(u16 h) {
    u32 x = ((u32)h) << 16; float f;
    __builtin_memcpy(&f, &x, 4);
    return f;
}
__device__ inline void gld16(const u16* g, u16* l) {
    __builtin_amdgcn_global_load_lds(
        (const __attribute__((address_space(1))) void*)(g),
        (__attribute__((address_space(3))) void*)(l), 16, 0, 0);
}
template <int N>
__device__ inline void wait_vmcnt() {
    if constexpr (N == 0)      asm volatile("s_waitcnt vmcnt(0)" ::: "memory");
    else if constexpr (N == 4) asm volatile("s_waitcnt vmcnt(4)" ::: "memory");
    else if constexpr (N == 8) asm volatile("s_waitcnt vmcnt(8)" ::: "memory");
}

// ---------------- descriptors ----------------
struct GDesc {
    const u16* A; const u16* Bt; const float* bias;
    void* out0; u16* aux0; u16* aux1;
    int lda, ldb, ldc, K, ntx, mode, rshift, tile_end;
};
struct GPack { int n; int pad[3]; GDesc d[8]; };

struct ADesc { const u16* Q; const u16* K; const u16* Vt; u16* O; int Rq, nk, tile_end, q0b; };
struct APack { int n; int pad[3]; ADesc d[2]; };

struct WDesc { const float* src; u16* dst; int ldn, K, tx_, tile_end; };
struct WPack { int n; int pad[3]; WDesc d[12]; };

struct CvtA { const float* a; u16* da; int na8; const float* b; u16* db; };

// ---------------- gemm path ----------------
// modes: 0 fp32+bias | 1 bf16+bias | 2 gelu+bf16 | 3 qkv split | 4 kv split
//        5 bf16 partial (no bias) | 6 bf16+bias causal-shifted rows
// BK=64 rows: 64 u16 chunk-swizzled LDS[R][c]=glob[R][c^(R&7)] (8 chunks).
// BK=32 rows: 32 u16 chunk-swizzled LDS[R][c]=glob[R][c^((R>>1)&3)] (4 chunks).
template <int TMT>
__device__ __forceinline__ void gemm_body(const GPack& pk, int bid, u16* smem)
{
    constexpr int TM = TMT * 16;
    constexpr int W = TMT / 2;
    constexpr int BK = (TMT == 8) ? 32 : 64;
    constexpr int BUF = TM * BK;       // u16 per buffer per operand
    constexpr int NLD = (TM * BK / 2048) * 2;  // gld16 per wave per stage (4)
    u16* As = smem;
    u16* Bs = smem + 2 * BUF;

    int di = 0;
    while (bid >= pk.d[di].tile_end) ++di;
    const GDesc g = pk.d[di];
    const int base = di ? pk.d[di - 1].tile_end : 0;
    const int local = bid - base;

    // XCD-strip + 4x4-superblock tile order (total%8==0, nty%4==0).
    const int total = g.tile_end - base;
    const int tpx = total >> 3;
    const int T = (local & 7) * tpx + (local >> 3);
    const int tx = (T >> 2) % g.ntx;
    const int ty = ((T / (g.ntx << 2)) << 2) + (T & 3);
    const int row0 = ty * TM, col0 = tx * TM;

    const int t = threadIdx.x;
    const int wave = t >> 6, lane = t & 63;
    const int l15 = lane & 15, quad = lane >> 4;
    const int wm = (wave >> 1) * W * 16, wn = (wave & 1) * W * 16;

    // staging addresses (swizzled global source, linear LDS dest)
    int srow, ssw;
    if constexpr (BK == 64) {
        srow = wave * 8 + (lane >> 3);
        ssw = ((lane & 7) ^ (lane >> 3)) * 8;
    } else {
        srow = wave * 32 + (lane >> 2);
        ssw = ((lane & 3) ^ ((lane >> 3) & 3)) * 8;
    }
    const u16* Ag = g.A + (long long)(row0 + srow) * g.lda + ssw;
    const u16* Bg = g.Bt + (long long)(col0 + srow) * g.ldb + ssw;

    f32x4 acc[W][W];
#pragma unroll
    for (int i = 0; i < W; ++i)
#pragma unroll
        for (int j = 0; j < W; ++j) {
            acc[i][j][0] = 0.f; acc[i][j][1] = 0.f;
            acc[i][j][2] = 0.f; acc[i][j][3] = 0.f;
        }

    auto stage = [&](int buf, int k0) {
        if constexpr (BK == 64) {
#pragma unroll
            for (int r = 0; r < TM / 32; ++r) {
                gld16(Ag + (long long)r * 32 * g.lda + k0, As + buf * BUF + r * 2048 + wave * 512);
                gld16(Bg + (long long)r * 32 * g.ldb + k0, Bs + buf * BUF + r * 2048 + wave * 512);
            }
        } else {
#pragma unroll
            for (int r = 0; r < 2; ++r) {
                gld16(Ag + (long long)r * 16 * g.lda + k0, As + buf * BUF + wave * 1024 + r * 512);
                gld16(Bg + (long long)r * 16 * g.ldb + k0, Bs + buf * BUF + wave * 1024 + r * 512);
            }
        }
    };
    auto compute = [&](int buf) {
        const u16* Ab = As + buf * BUF;
        const u16* Bb = Bs + buf * BUF;
        if constexpr (BK == 64) {
            const int c0 = (quad ^ (l15 & 7)) * 8;
#pragma unroll
            for (int kc = 0; kc < 2; ++kc) {
                const int cc = kc ? (c0 ^ 32) : c0;
                bf16x8 af[W], bfr[W];
#pragma unroll
                for (int i = 0; i < W; ++i) {
                    af[i]  = *(const bf16x8*)(Ab + (wm + i * 16 + l15) * 64 + cc);
                    bfr[i] = *(const bf16x8*)(Bb + (wn + i * 16 + l15) * 64 + cc);
                }
#pragma unroll
                for (int i = 0; i < W; ++i)
#pragma unroll
                    for (int j = 0; j < W; ++j)
                        acc[i][j] = __builtin_amdgcn_mfma_f32_16x16x32_bf16(af[i], bfr[j], acc[i][j], 0, 0, 0);
            }
        } else {
            const int cc = (quad ^ ((l15 >> 1) & 3)) * 8;
            bf16x8 af[W], bfr[W];
#pragma unroll
            for (int i = 0; i < W; ++i) {
                af[i]  = *(const bf16x8*)(Ab + (wm + i * 16 + l15) * 32 + cc);
                bfr[i] = *(const bf16x8*)(Bb + (wn + i * 16 + l15) * 32 + cc);
            }
#pragma unroll
            for (int i = 0; i < W; ++i)
#pragma unroll
                for (int j = 0; j < W; ++j)
                    acc[i][j] = __builtin_amdgcn_mfma_f32_16x16x32_bf16(af[i], bfr[j], acc[i][j], 0, 0, 0);
        }
    };

    // counted-vmcnt 2-deep pipeline (loads for t+1 in flight across barriers)
    const int nt = g.K / BK;
    stage(0, 0);
    for (int tt = 0; tt < nt; ++tt) {
        const int cur = tt & 1;
        if (tt + 1 < nt) {
            stage(cur ^ 1, (tt + 1) * BK);
            wait_vmcnt<NLD>();
        } else {
            wait_vmcnt<0>();
        }
        __builtin_amdgcn_sched_barrier(0);
        __builtin_amdgcn_s_barrier();
        __builtin_amdgcn_sched_barrier(0);
        compute(cur);
        __builtin_amdgcn_sched_barrier(0);
        __builtin_amdgcn_s_barrier();
    }

    const int rmask = (1 << g.rshift) - 1;
#pragma unroll
    for (int i = 0; i < W; ++i)
#pragma unroll
        for (int j = 0; j < W; ++j)
#pragma unroll
            for (int r = 0; r < 4; ++r) {
                int m = row0 + wm + i * 16 + quad * 4 + r;
                int n = col0 + wn + j * 16 + l15;
                float v = acc[i][j][r];
                if (g.mode != 5) v += g.bias[n];
                if (g.mode == 0) {
                    ((float*)g.out0)[(long long)m * g.ldc + n] = v;
                } else if (g.mode == 1 || g.mode == 5) {
                    ((u16*)g.out0)[(long long)m * g.ldc + n] = f2bf(v);
                } else if (g.mode == 2) {
                    float x3 = v * v * v;
                    v = 0.5f * v * (1.f + tanhf(0.7978845608028654f * (v + 0.044715f * x3)));
                    ((u16*)g.out0)[(long long)m * g.ldc + n] = f2bf(v);
                } else if (g.mode == 3) {
                    u16 h = f2bf(v);
                    if (n < 512) ((u16*)g.out0)[(long long)m * 512 + n] = h;
                    else if (n < 1024) g.aux0[(long long)m * 512 + (n - 512)] = h;
                    else {
                        int d = n - 1024;
                        int bb = m >> g.rshift, rr = m & rmask;
                        g.aux1[((long long)((bb * 8 + (d >> 6)) * 64 + (d & 63)) << g.rshift) + rr] = h;
                    }
                } else if (g.mode == 4) {
                    u16 h = f2bf(v);
                    if (n < 512) ((u16*)g.out0)[(long long)m * 512 + n] = h;
                    else {
                        int d = n - 512;
                        int bb = m >> g.rshift, rr = m & rmask;
                        g.aux1[((long long)((bb * 8 + (d >> 6)) * 64 + (d & 63)) << g.rshift) + rr] = h;
                    }
                } else {  // mode 6: causal shift fused
                    int t9 = m & 511;
                    if (t9 != 511) ((u16*)g.out0)[(long long)(m + 1) * g.ldc + n] = f2bf(v);
                    if (t9 == 0)  ((u16*)g.out0)[(long long)m * g.ldc + n] = 0;
                }
            }
}

// ---------------- attention path (r11: QBLK=64, Qs in LDS) ----------------
#define ALD 72

__device__ __forceinline__ void attn_body(const APack& pk, int bid, u16* smem, float prescale)
{
    // LDS carve (u16 units): Qs 4096 | Ks 2x4096 | Vts 2x4096 | Ps 4x16xALD
    u16* Qs  = smem;
    u16* Ks  = smem + 4096;
    u16* Vts = smem + 12288;
    u16* Psb = smem + 20480;

    int di = 0;
    while (bid >= pk.d[di].tile_end) ++di;
    const ADesc g = pk.d[di];
    const int base = di ? pk.d[di - 1].tile_end : 0;
    const int local = bid - base;

    const int t = threadIdx.x;
    const int wave = t >> 6, lane = t & 63;
    const int l15 = lane & 15, quad = lane >> 4;
    const int bh = local & 15, b = bh >> 3, h = bh & 7;
    const int q0 = g.q0b + (local >> 4) * 64;
    const int nk = g.nk;

    const int srow = wave * 8 + (lane >> 3);
    const int ssw = (((lane & 7) ^ (lane >> 3))) * 8;
    const int c0 = (quad ^ (l15 & 7)) * 8;

    const u16* Qg = g.Q + ((long long)(b * g.Rq + q0 + srow) << 9) + h * 64 + ssw;
    const u16* Kg = g.K + ((long long)(b * nk + srow) << 9) + h * 64 + ssw;
    const u16* Vg = g.Vt + (long long)bh * 64 * nk + (long long)srow * nk + ssw;

    auto stage = [&](int buf, int kt) {
#pragma unroll
        for (int r = 0; r < 2; ++r) {
            gld16(Kg + ((long long)(kt + r * 32) << 9), Ks + buf * 4096 + r * 2048 + wave * 512);
            gld16(Vg + (long long)r * 32 * nk + kt, Vts + buf * 4096 + r * 2048 + wave * 512);
        }
    };

    // prologue: Q (2 loads) then K/V tile 0 (4 loads)
#pragma unroll
    for (int r = 0; r < 2; ++r)
        gld16(Qg + ((long long)r * 32 << 9), Qs + r * 2048 + wave * 512);
    stage(0, 0);
    wait_vmcnt<4>();                    // Q landed (tile-0 loads still flying)
    __builtin_amdgcn_sched_barrier(0);
    __builtin_amdgcn_s_barrier();
    __builtin_amdgcn_sched_barrier(0);

    bf16x8 qf[2];
    qf[0] = *(const bf16x8*)(Qs + (wave * 16 + l15) * 64 + c0);
    qf[1] = *(const bf16x8*)(Qs + (wave * 16 + l15) * 64 + (c0 ^ 32));

    f32x4 Oacc[4];
#pragma unroll
    for (int nt2 = 0; nt2 < 4; ++nt2) { Oacc[nt2][0] = 0.f; Oacc[nt2][1] = 0.f; Oacc[nt2][2] = 0.f; Oacc[nt2][3] = 0.f; }
    float lr[4] = {0.f, 0.f, 0.f, 0.f};

    u16* Pw = Psb + wave * 16 * ALD;

    auto acompute = [&](int buf) {
        const u16* Kb = Ks + buf * 4096;
        const u16* Vb = Vts + buf * 4096;
#pragma unroll
        for (int k16 = 0; k16 < 4; ++k16) {
            f32x4 s;
            s[0] = 0.f; s[1] = 0.f; s[2] = 0.f; s[3] = 0.f;
            bf16x8 kf0 = *(const bf16x8*)(Kb + (k16 * 16 + l15) * 64 + c0);
            bf16x8 kf1 = *(const bf16x8*)(Kb + (k16 * 16 + l15) * 64 + (c0 ^ 32));
            __builtin_amdgcn_s_setprio(1);
            s = __builtin_amdgcn_mfma_f32_16x16x32_bf16(qf[0], kf0, s, 0, 0, 0);
            s = __builtin_amdgcn_mfma_f32_16x16x32_bf16(qf[1], kf1, s, 0, 0, 0);
            __builtin_amdgcn_s_setprio(0);
#pragma unroll
            for (int r = 0; r < 4; ++r) {
                float p = exp2f(s[r] * prescale);
                lr[r] += p;
                Pw[(quad * 4 + r) * ALD + k16 * 16 + l15] = f2bf(p);
            }
        }
        bf16x8 pf0 = *(const bf16x8*)(Pw + l15 * ALD + quad * 8);
        bf16x8 pf1 = *(const bf16x8*)(Pw + l15 * ALD + 32 + quad * 8);
        __builtin_amdgcn_s_setprio(1);
#pragma unroll
        for (int nt2 = 0; nt2 < 4; ++nt2) {
            bf16x8 vf0 = *(const bf16x8*)(Vb + (nt2 * 16 + l15) * 64 + c0);
            bf16x8 vf1 = *(const bf16x8*)(Vb + (nt2 * 16 + l15) * 64 + (c0 ^ 32));
            Oacc[nt2] = __builtin_amdgcn_mfma_f32_16x16x32_bf16(pf0, vf0, Oacc[nt2], 0, 0, 0);
            Oacc[nt2] = __builtin_amdgcn_mfma_f32_16x16x32_bf16(pf1, vf1, Oacc[nt2], 0, 0, 0);
        }
        __builtin_amdgcn_s_setprio(0);
    };

    const int nt = nk >> 6;
    for (int tt = 0; tt < nt; ++tt) {
        const int cur = tt & 1;
        if (tt + 1 < nt) {
            stage(cur ^ 1, (tt + 1) << 6);
            wait_vmcnt<4>();
        } else {
            wait_vmcnt<0>();
        }
        __builtin_amdgcn_sched_barrier(0);
        __builtin_amdgcn_s_barrier();
        __builtin_amdgcn_sched_barrier(0);
        acompute(cur);
        __builtin_amdgcn_sched_barrier(0);
        __builtin_amdgcn_s_barrier();
    }

    float inv[4];
#pragma unroll
    for (int r = 0; r < 4; ++r) {
        float s = lr[r];
#pragma unroll
        for (int off = 1; off < 16; off <<= 1) s += __shfl_xor(s, off);
        inv[r] = 1.f / s;
    }

    u16* Ob = g.O + ((long long)(b * g.Rq + q0 + wave * 16 + quad * 4) << 9) + h * 64;
#pragma unroll
    for (int nt2 = 0; nt2 < 4; ++nt2)
#pragma unroll
        for (int r = 0; r < 4; ++r)
            Ob[(long long)r * 512 + nt2 * 16 + l15] = f2bf(Oacc[nt2][r] * inv[r]);
}

// ---------------- weight transpose path ----------------
__device__ __forceinline__ void wt_body(const WPack& pk, int bid, u16* smem)
{
    float* T = (float*)smem;           // [64][68]
    int di = 0;
    while (bid >= pk.d[di].tile_end) ++di;
    const WDesc g = pk.d[di];
    const int base = di ? pk.d[di - 1].tile_end : 0;
    const int local = bid - base;
    const int k0 = (local % g.tx_) * 64;
    const int n0 = (local / g.tx_) * 64;
    const int t = threadIdx.x;
#pragma unroll
    for (int i = 0; i < 4; ++i) {
        int idx = t + i * 256;
        int r = idx >> 4, c4 = idx & 15;
        float4 v = *(const float4*)(g.src + (long long)(k0 + r) * g.ldn + n0 + c4 * 4);
        T[r * 68 + c4 * 4 + 0] = v.x; T[r * 68 + c4 * 4 + 1] = v.y;
        T[r * 68 + c4 * 4 + 2] = v.z; T[r * 68 + c4 * 4 + 3] = v.w;
    }
    __syncthreads();
#pragma unroll
    for (int i = 0; i < 4; ++i) {
        int idx = t + i * 256;
        int rn = idx >> 4, k4 = idx & 15;
        uint2 u;
        u.x = pack2(T[(k4 * 4 + 0) * 68 + rn], T[(k4 * 4 + 1) * 68 + rn]);
        u.y = pack2(T[(k4 * 4 + 2) * 68 + rn], T[(k4 * 4 + 3) * 68 + rn]);
        *(uint2*)(g.dst + (long long)(n0 + rn) * g.K + k0 + k4 * 4) = u;
    }
}

// ---------------- cvt path ----------------
__device__ __forceinline__ void cvt_body(const CvtA& cv, int bid)
{
    int i = bid * 256 + threadIdx.x;
    const float* s; u16* d;
    if (i < cv.na8) { s = cv.a + (long long)i * 8; d = cv.da + (long long)i * 8; }
    else { s = cv.b + (long long)(i - cv.na8) * 8; d = cv.db + (long long)(i - cv.na8) * 8; }
    float4 x = *(const float4*)s;
    float4 y = *(const float4*)(s + 4);
    uint4 u;
    u.x = pack2(x.x, x.y); u.y = pack2(x.z, x.w);
    u.z = pack2(y.x, y.y); u.w = pack2(y.z, y.w);
    *(uint4*)d = u;
}

// ---------------- fat dispatcher ----------------
template <int TMT>
__global__ __launch_bounds__(256)
void fat_multi(APack ap, GPack gp, WPack wp, CvtA cv,
               int na, int ngm, int nwt, float prescale)
{
    constexpr int BK = (TMT == 8) ? 32 : 64;
    constexpr int GB = 2 * (TMT * 16 * BK * 2) * 2;       // gemm LDS bytes
    // fat<8> carries only gemm (+wt needs 17408B); fat<4> unions with attn.
    constexpr int MIN = (TMT == 8) ? 17408 : 50176;
    constexpr int SB = (GB > MIN) ? GB : MIN;
    __shared__ __align__(16) u16 smem[SB / 2];
    int bid = blockIdx.x;
    if (bid < na) { attn_body(ap, bid, smem, prescale); return; }
    bid -= na;
    if (bid < ngm) { gemm_body<TMT>(gp, bid, smem); return; }
    bid -= ngm;
    if (bid < nwt) { wt_body(wp, bid, smem); return; }
    cvt_body(cv, bid - nwt);
}

// ---------------- launch ----------------
extern "C" void kernel_launch(void* const* d_in, const int* in_sizes, int n_in,
                              void* d_out, int out_size, void* d_ws, size_t ws_size,
                              hipStream_t stream)
{
    const float* x_fast      = (const float*)d_in[0];
    const float* x_slow      = (const float*)d_in[1];
    const float* fself_wqkv  = (const float*)d_in[2];
    const float* fself_bqkv  = (const float*)d_in[3];
    const float* fself_wo    = (const float*)d_in[4];
    const float* fself_bo    = (const float*)d_in[5];
    const float* fcross_wqkv = (const float*)d_in[6];
    const float* fcross_bqkv = (const float*)d_in[7];
    const float* fcross_wo   = (const float*)d_in[8];
    const float* fcross_bo   = (const float*)d_in[9];
    const float* sself_wqkv  = (const float*)d_in[10];
    const float* sself_bqkv  = (const float*)d_in[11];
    const float* sself_wo    = (const float*)d_in[12];
    const float* sself_bo    = (const float*)d_in[13];
    const float* scross_wqkv = (const float*)d_in[14];
    const float* scross_bqkv = (const float*)d_in[15];
    const float* scross_wo   = (const float*)d_in[16];
    const float* scross_bo   = (const float*)d_in[17];
    const float* lift_w      = (const float*)d_in[18];
    const float* lift_b      = (const float*)d_in[19];
    const float* pool_w1     = (const float*)d_in[20];
    const float* pool_b1     = (const float*)d_in[21];
    const float* pool_w2     = (const float*)d_in[22];
    const float* pool_b2     = (const float*)d_in[23];

    float* out = (float*)d_out;
    float* zf = out;                       // (2,2048,1024) fp32
    float* zs = out + 2LL * 2048 * 1024;   // (2,512,1024) fp32

    float* ws = (float*)d_ws;
    // ---- ws arena (fl offsets) ----
    u16* pw1T     = (u16*)(ws + 0);          // 4,194,304 fl (dead after L1)
    u16* wqkvT_f  = (u16*)(ws + 4194304);
    u16* wqkvT_c  = (u16*)(ws + 4587520);
    u16* wqkvT_s  = (u16*)(ws + 4980736);
    u16* wqkvT_sc = (u16*)(ws + 5373952);
    u16* liftT    = (u16*)(ws + 5767168);
    u16* pw2T     = (u16*)(ws + 6029312);
    u16* woT_f    = (u16*)(ws + 6553600);
    u16* woT_c    = (u16*)(ws + 6684672);
    u16* woT_s    = (u16*)(ws + 6815744);
    u16* woT_sc   = (u16*)(ws + 6946816);
    u16* xfb      = (u16*)(ws + 7077888);    // 2,097,152 fl (dead after L1)
    u16* xsb      = (u16*)(ws + 9175040);
    u16* q1       = (u16*)(ws + 9699328);    // 1,048,576 fl each
    u16* k1       = (u16*)(ws + 10747904);
    u16* vt1      = (u16*)(ws + 11796480);
    u16* qs       = (u16*)(ws + 12845056);   // 262,144 fl each
    u16* ks       = (u16*)(ws + 13107200);
    u16* vts      = (u16*)(ws + 13369344);
    u16* qcs      = (u16*)(ws + 13631488);   // ends 13,893,632
    // reuse of dead pw1T region after L2 starts (k2/vt2 written in L2):
    u16* k2    = (u16*)(ws + 0);
    u16* vt2   = (u16*)(ws + 262144);
    u16* sbufS = (u16*)(ws + 524288);
    u16* kcs   = (u16*)(ws + 786432);
    u16* vtcs  = (u16*)(ws + 1048576);
    u16* fo1   = (u16*)(ws + 1310720);       // 1,048,576 fl
    u16* fo2   = (u16*)(ws + 2359296);
    u16* so1   = (u16*)(ws + 3407872);
    u16* so2   = (u16*)(ws + 3670016);       // ends 3,932,160
    // d_out zf region as scratch (dead before L4 writes zf):
    u16* q2   = (u16*)(out + 0);             // 1,048,576 fl (dead after L3)
    u16* ybuf = (u16*)(out + 1048576);       // 262,144 fl  (dead after L2)
    u16* hbuf = (u16*)(out + 1310720);       // 1,048,576 fl (gelu(pool1) bf16)

    const float PRESCALE = 0.125f * 1.4426950408889634f;
    APack a_null{}; GPack g_null{}; WPack w_null{}; CvtA cv_null{};

    auto gl = [&](GPack& p, int i, const u16* A, int lda,
                  const u16* Bt, int ldb, const float* bias,
                  void* out0, int ldc, int M, int N, int K, int mode,
                  u16* aux0, u16* aux1, int rshift, int TM, int& te) {
        te += (M / TM) * (N / TM);
        p.d[i] = GDesc{A, Bt, bias, out0, aux0, aux1,
                       lda, ldb, ldc, K, N / TM, mode, rshift, te};
    };

    // ---- L0: ALL weight transposes + cvt ----
    {
        WPack wp; wp.n = 11; int te = 0, i = 0;
        auto add = [&](const float* s, u16* d, int ldn, int K, int N) {
            te += (K / 64) * (N / 64);
            wp.d[i++] = WDesc{s, d, ldn, K, K / 64, te};
        };
        add(pool_w1, pw1T, 2048, 4096, 2048);
        add(fself_wqkv, wqkvT_f, 1536, 512, 1536);
        add(fcross_wqkv, wqkvT_c, 1536, 512, 1536);
        add(sself_wqkv, wqkvT_s, 1536, 512, 1536);
        add(scross_wqkv, wqkvT_sc, 1536, 512, 1536);
        add(lift_w, liftT, 512, 1024, 512);
        add(pool_w2, pw2T, 512, 2048, 512);
        add(fself_wo, woT_f, 512, 512, 512);
        add(fcross_wo, woT_c, 512, 512, 512);
        add(sself_wo, woT_s, 512, 512, 512);
        add(scross_wo, woT_sc, 512, 512, 512);
        CvtA cv{x_fast, xfb, 524288, x_slow, xsb};
        hipLaunchKernelGGL(fat_multi<4>, dim3(te + 2560), dim3(256), 0, stream,
                           a_null, g_null, wp, cv, 0, 0, te, PRESCALE);
    }

    // ---- L1: input-side GEMMs (pool1 fused-gelu, full K; BK=32) ----
    {
        GPack p; p.n = 6; int te = 0;
        gl(p, 0, xfb, 4096, pw1T, 4096, pool_b1, hbuf, 2048,
           1024, 2048, 4096, 2, 0, 0, 0, 128, te);                    // pool1+gelu
        gl(p, 1, xfb, 1024, wqkvT_f, 512, fself_bqkv, q1, 512,
           4096, 1536, 512, 3, k1, vt1, 11, 128, te);                 // fself qkv
        gl(p, 2, xfb + 512, 1024, wqkvT_c, 512, fcross_bqkv, q2, 512,
           4096, 512, 512, 1, 0, 0, 0, 128, te);                      // fcross q
        gl(p, 3, xsb, 1024, wqkvT_s, 512, sself_bqkv, qs, 512,
           1024, 1536, 512, 3, ks, vts, 9, 128, te);                  // sself qkv
        gl(p, 4, xsb, 1024, liftT, 1024, lift_b, ybuf, 512,
           1024, 512, 1024, 1, 0, 0, 0, 128, te);                     // lift
        gl(p, 5, xsb + 512, 1024, wqkvT_sc, 512, scross_bqkv, qcs, 512,
           1024, 512, 512, 1, 0, 0, 0, 128, te);                      // scross q
        hipLaunchKernelGGL(fat_multi<8>, dim3(te), dim3(256), 0, stream,
                           a_null, p, w_null, cv_null, 0, te, 0, PRESCALE);
    }

    // ---- L2: fselfA-attn + sself-attn || {pool2, fcrossKV} ----
    {
        APack ap; ap.n = 2;
        ap.d[0] = ADesc{q1, k1, vt1, fo1, 2048, 2048, 256, 0};     // fself rows 0..1023
        ap.d[1] = ADesc{qs, ks, vts, so1, 512, 512, 384, 0};       // sself
        GPack p; p.n = 2; int te = 0;
        gl(p, 0, hbuf, 2048, pw2T, 2048, pool_b2, sbufS, 512,
           1024, 512, 2048, 6, 0, 0, 0, 64, te);                   // pool2 (shift)
        gl(p, 1, ybuf, 512, wqkvT_c + 512 * 512, 512, fcross_bqkv + 512, k2, 512,
           1024, 1024, 512, 4, 0, vt2, 9, 64, te);                 // fcross kv
        hipLaunchKernelGGL(fat_multi<4>, dim3(384 + te), dim3(256), 0, stream,
                           ap, p, w_null, cv_null, 384, te, 0, PRESCALE);
    }

    // ---- L3: fselfB-attn + fcross-attn || scrossKV ----
    {
        APack ap; ap.n = 2;
        ap.d[0] = ADesc{q1, k1, vt1, fo1, 2048, 2048, 256, 1024};  // fself rows 1024..2047
        ap.d[1] = ADesc{q2, k2, vt2, fo2, 2048, 512, 768, 0};      // fcross
        GPack p; p.n = 1; int te = 0;
        gl(p, 0, sbufS, 512, wqkvT_sc + 512 * 512, 512, scross_bqkv + 512, kcs, 512,
           1024, 1024, 512, 4, 0, vtcs, 9, 64, te);                // scross kv
        hipLaunchKernelGGL(fat_multi<4>, dim3(768 + te), dim3(256), 0, stream,
                           ap, p, w_null, cv_null, 768, te, 0, PRESCALE);
    }

    // ---- L4: scross-attn || out-proj {fself, fcross, sself} (TM=64) ----
    {
        APack ap; ap.n = 1;
        ap.d[0] = ADesc{qcs, kcs, vtcs, so2, 512, 512, 128, 0};    // scross
        GPack p; p.n = 3; int te = 0;
        gl(p, 0, fo1, 512, woT_f, 512, fself_bo, zf, 1024,
           4096, 512, 512, 0, 0, 0, 0, 64, te);
        gl(p, 1, fo2, 512, woT_c, 512, fcross_bo, zf + 512, 1024,
           4096, 512, 512, 0, 0, 0, 0, 64, te);
        gl(p, 2, so1, 512, woT_s, 512, sself_bo, zs, 1024,
           1024, 512, 512, 0, 0, 0, 0, 64, te);
        hipLaunchKernelGGL(fat_multi<4>, dim3(128 + te), dim3(256), 0, stream,
                           ap, p, w_null, cv_null, 128, te, 0, PRESCALE);
    }

    // ---- L5: out-proj scross (TM=64) ----
    {
        GPack p; p.n = 1; int te = 0;
        gl(p, 0, so2, 512, woT_sc, 512, scross_bo, zs + 512, 1024,
           1024, 512, 512, 0, 0, 0, 0, 64, te);
        hipLaunchKernelGGL(fat_multi<4>, dim3(te), dim3(256), 0, stream,
                           a_null, p, w_null, cv_null, 0, te, 0, PRESCALE);
    }
}

// Round 11
// 332.269 us; speedup vs baseline: 1.1770x; 1.1282x over previous
//
#include <hip/hip_runtime.h>
#include <hip/hip_bf16.h>

// Round 17: REVERT to r11 verbatim (333.4us, session best). 10-round search
// characterized every neighbor as worse:
//  - L1 pipeline: 2-deep/64KB/2blk = 78us; 3-deep/96KB/1blk = 174us;
//    2-deep BK=32/32KB/4blk = 121us  -> L1 is ~72% of L2-BW (25/34.5 TB/s
//    aggregate staged traffic), config-optimal.
//  - graph: r11's 6-launch chain-aware packing beat all repacks (r12/r13).
//  - attn QBLK=128 (r14) lost to grid-halving; split-K pool1 (r13) null.
//   L0 {wt-all + cvt}
//   L1 {pool1-fused(K=4096) + qkv/lift/q gemms}
//   L2 {fselfA-attn + sself-attn || pool2 + fcrossKV}
//   L3 {fselfB-attn + fcross-attn || scrossKV}
//   L4 {scross-attn || out-proj fself/fcross/sself}
//   L5 {out-proj scross}

typedef __attribute__((ext_vector_type(8))) short bf16x8;
typedef __attribute__((ext_vector_type(4))) float f32x4;
typedef unsigned short u16;
typedef unsigned int u32;

__device__ inline u16 f2bf(float f) {
    __hip_bfloat16 h = __float2bfloat16(f);
    return *reinterpret_cast<u16*>(&h);
}
__device__ inline u32 pack2(float a, float b) {
    return (u32)f2bf(a) | ((u32)f2bf(b) << 16);
}
__device__ inline float bf2f(u16 h) {
    u32 x = ((u32)h) << 16; float f;
    __builtin_memcpy(&f, &x, 4);
    return f;
}
__device__ inline void gld16(const u16* g, u16* l) {
    __builtin_amdgcn_global_load_lds(
        (const __attribute__((address_space(1))) void*)(g),
        (__attribute__((address_space(3))) void*)(l), 16, 0, 0);
}
template <int N>
__device__ inline void wait_vmcnt() {
    if constexpr (N == 0)      asm volatile("s_waitcnt vmcnt(0)" ::: "memory");
    else if constexpr (N == 4) asm volatile("s_waitcnt vmcnt(4)" ::: "memory");
    else if constexpr (N == 8) asm volatile("s_waitcnt vmcnt(8)" ::: "memory");
}

// ---------------- descriptors ----------------
struct GDesc {
    const u16* A; const u16* Bt; const float* bias;
    void* out0; u16* aux0; u16* aux1;
    int lda, ldb, ldc, K, ntx, mode, rshift, tile_end;
};
struct GPack { int n; int pad[3]; GDesc d[8]; };

struct ADesc { const u16* Q; const u16* K; const u16* Vt; u16* O; int Rq, nk, tile_end, q0b; };
struct APack { int n; int pad[3]; ADesc d[2]; };

struct WDesc { const float* src; u16* dst; int ldn, K, tx_, tile_end; };
struct WPack { int n; int pad[3]; WDesc d[12]; };

struct CvtA { const float* a; u16* da; int na8; const float* b; u16* db; };

// ---------------- gemm path ----------------
// modes: 0 fp32+bias | 1 bf16+bias | 2 gelu+bf16 | 3 qkv split | 4 kv split
//        5 bf16 partial (no bias) | 6 bf16+bias causal-shifted rows
// LDS rows are 64 u16 (128 B), chunk-swizzled: LDS[R][c] = glob[R][c^(R&7)].
template <int TMT>
__device__ __forceinline__ void gemm_body(const GPack& pk, int bid, u16* smem)
{
    constexpr int TM = TMT * 16;
    constexpr int W = TMT / 2;
    constexpr int BUF = TM * 64;       // u16 per buffer per operand
    constexpr int NLD = TM / 32 * 2;   // gld_lds per wave per stage
    u16* As = smem;
    u16* Bs = smem + 2 * BUF;

    int di = 0;
    while (bid >= pk.d[di].tile_end) ++di;
    const GDesc g = pk.d[di];
    const int base = di ? pk.d[di - 1].tile_end : 0;
    const int local = bid - base;

    // XCD-strip + 4x4-superblock tile order (total%8==0, nty%4==0).
    const int total = g.tile_end - base;
    const int tpx = total >> 3;
    const int T = (local & 7) * tpx + (local >> 3);
    const int tx = (T >> 2) % g.ntx;
    const int ty = ((T / (g.ntx << 2)) << 2) + (T & 3);
    const int row0 = ty * TM, col0 = tx * TM;

    const int t = threadIdx.x;
    const int wave = t >> 6, lane = t & 63;
    const int l15 = lane & 15, quad = lane >> 4;
    const int wm = (wave >> 1) * W * 16, wn = (wave & 1) * W * 16;

    const int srow = wave * 8 + (lane >> 3);
    const int ssw = (((lane & 7) ^ (lane >> 3))) * 8;
    const u16* Ag = g.A + (long long)(row0 + srow) * g.lda + ssw;
    const u16* Bg = g.Bt + (long long)(col0 + srow) * g.ldb + ssw;

    const int c0 = (quad ^ (l15 & 7)) * 8;

    f32x4 acc[W][W];
#pragma unroll
    for (int i = 0; i < W; ++i)
#pragma unroll
        for (int j = 0; j < W; ++j) {
            acc[i][j][0] = 0.f; acc[i][j][1] = 0.f;
            acc[i][j][2] = 0.f; acc[i][j][3] = 0.f;
        }

    auto stage = [&](int buf, int k0) {
#pragma unroll
        for (int r = 0; r < TM / 32; ++r) {
            gld16(Ag + (long long)r * 32 * g.lda + k0, As + buf * BUF + r * 2048 + wave * 512);
            gld16(Bg + (long long)r * 32 * g.ldb + k0, Bs + buf * BUF + r * 2048 + wave * 512);
        }
    };
    auto compute = [&](int buf) {
        const u16* Ab = As + buf * BUF;
        const u16* Bb = Bs + buf * BUF;
#pragma unroll
        for (int kc = 0; kc < 2; ++kc) {
            const int cc = kc ? (c0 ^ 32) : c0;
            bf16x8 af[W], bfr[W];
#pragma unroll
            for (int i = 0; i < W; ++i) {
                af[i]  = *(const bf16x8*)(Ab + (wm + i * 16 + l15) * 64 + cc);
                bfr[i] = *(const bf16x8*)(Bb + (wn + i * 16 + l15) * 64 + cc);
            }
#pragma unroll
            for (int i = 0; i < W; ++i)
#pragma unroll
                for (int j = 0; j < W; ++j)
                    acc[i][j] = __builtin_amdgcn_mfma_f32_16x16x32_bf16(af[i], bfr[j], acc[i][j], 0, 0, 0);
        }
    };

    const int nt = g.K >> 6;
    stage(0, 0);
    for (int tt = 0; tt < nt; ++tt) {
        const int cur = tt & 1;
        if (tt + 1 < nt) {
            stage(cur ^ 1, (tt + 1) << 6);
            wait_vmcnt<NLD>();
        } else {
            wait_vmcnt<0>();
        }
        __builtin_amdgcn_sched_barrier(0);
        __builtin_amdgcn_s_barrier();
        __builtin_amdgcn_sched_barrier(0);
        compute(cur);
        __builtin_amdgcn_sched_barrier(0);
        __builtin_amdgcn_s_barrier();
    }

    const int rmask = (1 << g.rshift) - 1;
#pragma unroll
    for (int i = 0; i < W; ++i)
#pragma unroll
        for (int j = 0; j < W; ++j)
#pragma unroll
            for (int r = 0; r < 4; ++r) {
                int m = row0 + wm + i * 16 + quad * 4 + r;
                int n = col0 + wn + j * 16 + l15;
                float v = acc[i][j][r];
                if (g.mode != 5) v += g.bias[n];
                if (g.mode == 0) {
                    ((float*)g.out0)[(long long)m * g.ldc + n] = v;
                } else if (g.mode == 1 || g.mode == 5) {
                    ((u16*)g.out0)[(long long)m * g.ldc + n] = f2bf(v);
                } else if (g.mode == 2) {
                    float x3 = v * v * v;
                    v = 0.5f * v * (1.f + tanhf(0.7978845608028654f * (v + 0.044715f * x3)));
                    ((u16*)g.out0)[(long long)m * g.ldc + n] = f2bf(v);
                } else if (g.mode == 3) {
                    u16 h = f2bf(v);
                    if (n < 512) ((u16*)g.out0)[(long long)m * 512 + n] = h;
                    else if (n < 1024) g.aux0[(long long)m * 512 + (n - 512)] = h;
                    else {
                        int d = n - 1024;
                        int bb = m >> g.rshift, rr = m & rmask;
                        g.aux1[((long long)((bb * 8 + (d >> 6)) * 64 + (d & 63)) << g.rshift) + rr] = h;
                    }
                } else if (g.mode == 4) {
                    u16 h = f2bf(v);
                    if (n < 512) ((u16*)g.out0)[(long long)m * 512 + n] = h;
                    else {
                        int d = n - 512;
                        int bb = m >> g.rshift, rr = m & rmask;
                        g.aux1[((long long)((bb * 8 + (d >> 6)) * 64 + (d & 63)) << g.rshift) + rr] = h;
                    }
                } else {  // mode 6: causal shift fused
                    int t9 = m & 511;
                    if (t9 != 511) ((u16*)g.out0)[(long long)(m + 1) * g.ldc + n] = f2bf(v);
                    if (t9 == 0)  ((u16*)g.out0)[(long long)m * g.ldc + n] = 0;
                }
            }
}

// ---------------- attention path ----------------
#define ALD 72

__device__ __forceinline__ void attn_body(const APack& pk, int bid, u16* smem, float prescale)
{
    // LDS carve (u16 units): Qs 4096 | Ks 2x4096 | Vts 2x4096 | Ps 4x16xALD
    u16* Qs  = smem;
    u16* Ks  = smem + 4096;
    u16* Vts = smem + 12288;
    u16* Psb = smem + 20480;

    int di = 0;
    while (bid >= pk.d[di].tile_end) ++di;
    const ADesc g = pk.d[di];
    const int base = di ? pk.d[di - 1].tile_end : 0;
    const int local = bid - base;

    const int t = threadIdx.x;
    const int wave = t >> 6, lane = t & 63;
    const int l15 = lane & 15, quad = lane >> 4;
    const int bh = local & 15, b = bh >> 3, h = bh & 7;
    const int q0 = g.q0b + (local >> 4) * 64;
    const int nk = g.nk;

    const int srow = wave * 8 + (lane >> 3);
    const int ssw = (((lane & 7) ^ (lane >> 3))) * 8;
    const int c0 = (quad ^ (l15 & 7)) * 8;

    const u16* Qg = g.Q + ((long long)(b * g.Rq + q0 + srow) << 9) + h * 64 + ssw;
    const u16* Kg = g.K + ((long long)(b * nk + srow) << 9) + h * 64 + ssw;
    const u16* Vg = g.Vt + (long long)bh * 64 * nk + (long long)srow * nk + ssw;

    auto stage = [&](int buf, int kt) {
#pragma unroll
        for (int r = 0; r < 2; ++r) {
            gld16(Kg + ((long long)(kt + r * 32) << 9), Ks + buf * 4096 + r * 2048 + wave * 512);
            gld16(Vg + (long long)r * 32 * nk + kt, Vts + buf * 4096 + r * 2048 + wave * 512);
        }
    };

    // prologue: Q (2 loads) then K/V tile 0 (4 loads)
#pragma unroll
    for (int r = 0; r < 2; ++r)
        gld16(Qg + ((long long)r * 32 << 9), Qs + r * 2048 + wave * 512);
    stage(0, 0);
    wait_vmcnt<4>();                    // Q landed (tile-0 loads still flying)
    __builtin_amdgcn_sched_barrier(0);
    __builtin_amdgcn_s_barrier();
    __builtin_amdgcn_sched_barrier(0);

    bf16x8 qf[2];
    qf[0] = *(const bf16x8*)(Qs + (wave * 16 + l15) * 64 + c0);
    qf[1] = *(const bf16x8*)(Qs + (wave * 16 + l15) * 64 + (c0 ^ 32));

    f32x4 Oacc[4];
#pragma unroll
    for (int nt2 = 0; nt2 < 4; ++nt2) { Oacc[nt2][0] = 0.f; Oacc[nt2][1] = 0.f; Oacc[nt2][2] = 0.f; Oacc[nt2][3] = 0.f; }
    float lr[4] = {0.f, 0.f, 0.f, 0.f};

    u16* Pw = Psb + wave * 16 * ALD;

    auto acompute = [&](int buf) {
        const u16* Kb = Ks + buf * 4096;
        const u16* Vb = Vts + buf * 4096;
#pragma unroll
        for (int k16 = 0; k16 < 4; ++k16) {
            f32x4 s;
            s[0] = 0.f; s[1] = 0.f; s[2] = 0.f; s[3] = 0.f;
            bf16x8 kf0 = *(const bf16x8*)(Kb + (k16 * 16 + l15) * 64 + c0);
            bf16x8 kf1 = *(const bf16x8*)(Kb + (k16 * 16 + l15) * 64 + (c0 ^ 32));
            __builtin_amdgcn_s_setprio(1);
            s = __builtin_amdgcn_mfma_f32_16x16x32_bf16(qf[0], kf0, s, 0, 0, 0);
            s = __builtin_amdgcn_mfma_f32_16x16x32_bf16(qf[1], kf1, s, 0, 0, 0);
            __builtin_amdgcn_s_setprio(0);
#pragma unroll
            for (int r = 0; r < 4; ++r) {
                float p = exp2f(s[r] * prescale);
                lr[r] += p;
                Pw[(quad * 4 + r) * ALD + k16 * 16 + l15] = f2bf(p);
            }
        }
        bf16x8 pf0 = *(const bf16x8*)(Pw + l15 * ALD + quad * 8);
        bf16x8 pf1 = *(const bf16x8*)(Pw + l15 * ALD + 32 + quad * 8);
        __builtin_amdgcn_s_setprio(1);
#pragma unroll
        for (int nt2 = 0; nt2 < 4; ++nt2) {
            bf16x8 vf0 = *(const bf16x8*)(Vb + (nt2 * 16 + l15) * 64 + c0);
            bf16x8 vf1 = *(const bf16x8*)(Vb + (nt2 * 16 + l15) * 64 + (c0 ^ 32));
            Oacc[nt2] = __builtin_amdgcn_mfma_f32_16x16x32_bf16(pf0, vf0, Oacc[nt2], 0, 0, 0);
            Oacc[nt2] = __builtin_amdgcn_mfma_f32_16x16x32_bf16(pf1, vf1, Oacc[nt2], 0, 0, 0);
        }
        __builtin_amdgcn_s_setprio(0);
    };

    const int nt = nk >> 6;
    for (int tt = 0; tt < nt; ++tt) {
        const int cur = tt & 1;
        if (tt + 1 < nt) {
            stage(cur ^ 1, (tt + 1) << 6);
            wait_vmcnt<4>();
        } else {
            wait_vmcnt<0>();
        }
        __builtin_amdgcn_sched_barrier(0);
        __builtin_amdgcn_s_barrier();
        __builtin_amdgcn_sched_barrier(0);
        acompute(cur);
        __builtin_amdgcn_sched_barrier(0);
        __builtin_amdgcn_s_barrier();
    }

    float inv[4];
#pragma unroll
    for (int r = 0; r < 4; ++r) {
        float s = lr[r];
#pragma unroll
        for (int off = 1; off < 16; off <<= 1) s += __shfl_xor(s, off);
        inv[r] = 1.f / s;
    }

    u16* Ob = g.O + ((long long)(b * g.Rq + q0 + wave * 16 + quad * 4) << 9) + h * 64;
#pragma unroll
    for (int nt2 = 0; nt2 < 4; ++nt2)
#pragma unroll
        for (int r = 0; r < 4; ++r)
            Ob[(long long)r * 512 + nt2 * 16 + l15] = f2bf(Oacc[nt2][r] * inv[r]);
}

// ---------------- weight transpose path ----------------
__device__ __forceinline__ void wt_body(const WPack& pk, int bid, u16* smem)
{
    float* T = (float*)smem;           // [64][68]
    int di = 0;
    while (bid >= pk.d[di].tile_end) ++di;
    const WDesc g = pk.d[di];
    const int base = di ? pk.d[di - 1].tile_end : 0;
    const int local = bid - base;
    const int k0 = (local % g.tx_) * 64;
    const int n0 = (local / g.tx_) * 64;
    const int t = threadIdx.x;
#pragma unroll
    for (int i = 0; i < 4; ++i) {
        int idx = t + i * 256;
        int r = idx >> 4, c4 = idx & 15;
        float4 v = *(const float4*)(g.src + (long long)(k0 + r) * g.ldn + n0 + c4 * 4);
        T[r * 68 + c4 * 4 + 0] = v.x; T[r * 68 + c4 * 4 + 1] = v.y;
        T[r * 68 + c4 * 4 + 2] = v.z; T[r * 68 + c4 * 4 + 3] = v.w;
    }
    __syncthreads();
#pragma unroll
    for (int i = 0; i < 4; ++i) {
        int idx = t + i * 256;
        int rn = idx >> 4, k4 = idx & 15;
        uint2 u;
        u.x = pack2(T[(k4 * 4 + 0) * 68 + rn], T[(k4 * 4 + 1) * 68 + rn]);
        u.y = pack2(T[(k4 * 4 + 2) * 68 + rn], T[(k4 * 4 + 3) * 68 + rn]);
        *(uint2*)(g.dst + (long long)(n0 + rn) * g.K + k0 + k4 * 4) = u;
    }
}

// ---------------- cvt path ----------------
__device__ __forceinline__ void cvt_body(const CvtA& cv, int bid)
{
    int i = bid * 256 + threadIdx.x;
    const float* s; u16* d;
    if (i < cv.na8) { s = cv.a + (long long)i * 8; d = cv.da + (long long)i * 8; }
    else { s = cv.b + (long long)(i - cv.na8) * 8; d = cv.db + (long long)(i - cv.na8) * 8; }
    float4 x = *(const float4*)s;
    float4 y = *(const float4*)(s + 4);
    uint4 u;
    u.x = pack2(x.x, x.y); u.y = pack2(x.z, x.w);
    u.z = pack2(y.x, y.y); u.w = pack2(y.z, y.w);
    *(uint4*)d = u;
}

// ---------------- fat dispatcher ----------------
template <int TMT>
__global__ __launch_bounds__(256)
void fat_multi(APack ap, GPack gp, WPack wp, CvtA cv,
               int na, int ngm, int nwt, float prescale)
{
    constexpr int GB = 2 * 2 * (TMT * 16 * 64) * 2;       // gemm LDS bytes
    constexpr int SB = (GB > 50176) ? GB : 50176;         // union with attn/wt
    __shared__ __align__(16) u16 smem[SB / 2];
    int bid = blockIdx.x;
    if (bid < na) { attn_body(ap, bid, smem, prescale); return; }
    bid -= na;
    if (bid < ngm) { gemm_body<TMT>(gp, bid, smem); return; }
    bid -= ngm;
    if (bid < nwt) { wt_body(wp, bid, smem); return; }
    cvt_body(cv, bid - nwt);
}

// ---------------- launch ----------------
extern "C" void kernel_launch(void* const* d_in, const int* in_sizes, int n_in,
                              void* d_out, int out_size, void* d_ws, size_t ws_size,
                              hipStream_t stream)
{
    const float* x_fast      = (const float*)d_in[0];
    const float* x_slow      = (const float*)d_in[1];
    const float* fself_wqkv  = (const float*)d_in[2];
    const float* fself_bqkv  = (const float*)d_in[3];
    const float* fself_wo    = (const float*)d_in[4];
    const float* fself_bo    = (const float*)d_in[5];
    const float* fcross_wqkv = (const float*)d_in[6];
    const float* fcross_bqkv = (const float*)d_in[7];
    const float* fcross_wo   = (const float*)d_in[8];
    const float* fcross_bo   = (const float*)d_in[9];
    const float* sself_wqkv  = (const float*)d_in[10];
    const float* sself_bqkv  = (const float*)d_in[11];
    const float* sself_wo    = (const float*)d_in[12];
    const float* sself_bo    = (const float*)d_in[13];
    const float* scross_wqkv = (const float*)d_in[14];
    const float* scross_bqkv = (const float*)d_in[15];
    const float* scross_wo   = (const float*)d_in[16];
    const float* scross_bo   = (const float*)d_in[17];
    const float* lift_w      = (const float*)d_in[18];
    const float* lift_b      = (const float*)d_in[19];
    const float* pool_w1     = (const float*)d_in[20];
    const float* pool_b1     = (const float*)d_in[21];
    const float* pool_w2     = (const float*)d_in[22];
    const float* pool_b2     = (const float*)d_in[23];

    float* out = (float*)d_out;
    float* zf = out;                       // (2,2048,1024) fp32
    float* zs = out + 2LL * 2048 * 1024;   // (2,512,1024) fp32

    float* ws = (float*)d_ws;
    // ---- ws arena (fl offsets) ----
    u16* pw1T     = (u16*)(ws + 0);          // 4,194,304 fl (dead after L1)
    u16* wqkvT_f  = (u16*)(ws + 4194304);
    u16* wqkvT_c  = (u16*)(ws + 4587520);
    u16* wqkvT_s  = (u16*)(ws + 4980736);
    u16* wqkvT_sc = (u16*)(ws + 5373952);
    u16* liftT    = (u16*)(ws + 5767168);
    u16* pw2T     = (u16*)(ws + 6029312);
    u16* woT_f    = (u16*)(ws + 6553600);
    u16* woT_c    = (u16*)(ws + 6684672);
    u16* woT_s    = (u16*)(ws + 6815744);
    u16* woT_sc   = (u16*)(ws + 6946816);
    u16* xfb      = (u16*)(ws + 7077888);    // 2,097,152 fl (dead after L2)
    u16* xsb      = (u16*)(ws + 9175040);
    u16* q1       = (u16*)(ws + 9699328);    // 1,048,576 fl each
    u16* k1       = (u16*)(ws + 10747904);
    u16* vt1      = (u16*)(ws + 11796480);
    u16* qs       = (u16*)(ws + 12845056);   // 262,144 fl each
    u16* ks       = (u16*)(ws + 13107200);
    u16* vts      = (u16*)(ws + 13369344);
    u16* qcs      = (u16*)(ws + 13631488);   // ends 13,893,632
    // reuse of dead pw1T region after L2 starts (k2/vt2 written in L2):
    u16* k2    = (u16*)(ws + 0);
    u16* vt2   = (u16*)(ws + 262144);
    u16* sbufS = (u16*)(ws + 524288);
    u16* kcs   = (u16*)(ws + 786432);
    u16* vtcs  = (u16*)(ws + 1048576);
    u16* fo1   = (u16*)(ws + 1310720);       // 1,048,576 fl
    u16* fo2   = (u16*)(ws + 2359296);
    u16* so1   = (u16*)(ws + 3407872);
    u16* so2   = (u16*)(ws + 3670016);       // ends 3,932,160
    // d_out zf region as scratch (dead before L4 writes zf):
    u16* q2   = (u16*)(out + 0);             // 1,048,576 fl (dead after L3)
    u16* ybuf = (u16*)(out + 1048576);       // 262,144 fl  (dead after L2)
    u16* hbuf = (u16*)(out + 1310720);       // 1,048,576 fl (gelu(pool1) bf16)

    const float PRESCALE = 0.125f * 1.4426950408889634f;
    APack a_null{}; GPack g_null{}; WPack w_null{}; CvtA cv_null{};

    auto gl = [&](GPack& p, int i, const u16* A, int lda,
                  const u16* Bt, int ldb, const float* bias,
                  void* out0, int ldc, int M, int N, int K, int mode,
                  u16* aux0, u16* aux1, int rshift, int TM, int& te) {
        te += (M / TM) * (N / TM);
        p.d[i] = GDesc{A, Bt, bias, out0, aux0, aux1,
                       lda, ldb, ldc, K, N / TM, mode, rshift, te};
    };

    // ---- L0: ALL weight transposes + cvt ----
    {
        WPack wp; wp.n = 11; int te = 0, i = 0;
        auto add = [&](const float* s, u16* d, int ldn, int K, int N) {
            te += (K / 64) * (N / 64);
            wp.d[i++] = WDesc{s, d, ldn, K, K / 64, te};
        };
        add(pool_w1, pw1T, 2048, 4096, 2048);
        add(fself_wqkv, wqkvT_f, 1536, 512, 1536);
        add(fcross_wqkv, wqkvT_c, 1536, 512, 1536);
        add(sself_wqkv, wqkvT_s, 1536, 512, 1536);
        add(scross_wqkv, wqkvT_sc, 1536, 512, 1536);
        add(lift_w, liftT, 512, 1024, 512);
        add(pool_w2, pw2T, 512, 2048, 512);
        add(fself_wo, woT_f, 512, 512, 512);
        add(fcross_wo, woT_c, 512, 512, 512);
        add(sself_wo, woT_s, 512, 512, 512);
        add(scross_wo, woT_sc, 512, 512, 512);
        CvtA cv{x_fast, xfb, 524288, x_slow, xsb};
        hipLaunchKernelGGL(fat_multi<4>, dim3(te + 2560), dim3(256), 0, stream,
                           a_null, g_null, wp, cv, 0, 0, te, PRESCALE);
    }

    // ---- L1: input-side GEMMs (pool1 fused-gelu, full K) ----
    {
        GPack p; p.n = 6; int te = 0;
        gl(p, 0, xfb, 4096, pw1T, 4096, pool_b1, hbuf, 2048,
           1024, 2048, 4096, 2, 0, 0, 0, 128, te);                    // pool1+gelu
        gl(p, 1, xfb, 1024, wqkvT_f, 512, fself_bqkv, q1, 512,
           4096, 1536, 512, 3, k1, vt1, 11, 128, te);                 // fself qkv
        gl(p, 2, xfb + 512, 1024, wqkvT_c, 512, fcross_bqkv, q2, 512,
           4096, 512, 512, 1, 0, 0, 0, 128, te);                      // fcross q
        gl(p, 3, xsb, 1024, wqkvT_s, 512, sself_bqkv, qs, 512,
           1024, 1536, 512, 3, ks, vts, 9, 128, te);                  // sself qkv
        gl(p, 4, xsb, 1024, liftT, 1024, lift_b, ybuf, 512,
           1024, 512, 1024, 1, 0, 0, 0, 128, te);                     // lift
        gl(p, 5, xsb + 512, 1024, wqkvT_sc, 512, scross_bqkv, qcs, 512,
           1024, 512, 512, 1, 0, 0, 0, 128, te);                      // scross q
        hipLaunchKernelGGL(fat_multi<8>, dim3(te), dim3(256), 0, stream,
                           a_null, p, w_null, cv_null, 0, te, 0, PRESCALE);
    }

    // ---- L2: fselfA-attn + sself-attn || {pool2, fcrossKV} ----
    {
        APack ap; ap.n = 2;
        ap.d[0] = ADesc{q1, k1, vt1, fo1, 2048, 2048, 256, 0};     // fself rows 0..1023
        ap.d[1] = ADesc{qs, ks, vts, so1, 512, 512, 384, 0};       // sself
        GPack p; p.n = 2; int te = 0;
        gl(p, 0, hbuf, 2048, pw2T, 2048, pool_b2, sbufS, 512,
           1024, 512, 2048, 6, 0, 0, 0, 64, te);                   // pool2 (shift)
        gl(p, 1, ybuf, 512, wqkvT_c + 512 * 512, 512, fcross_bqkv + 512, k2, 512,
           1024, 1024, 512, 4, 0, vt2, 9, 64, te);                 // fcross kv
        hipLaunchKernelGGL(fat_multi<4>, dim3(384 + te), dim3(256), 0, stream,
                           ap, p, w_null, cv_null, 384, te, 0, PRESCALE);
    }

    // ---- L3: fselfB-attn + fcross-attn || scrossKV ----
    {
        APack ap; ap.n = 2;
        ap.d[0] = ADesc{q1, k1, vt1, fo1, 2048, 2048, 256, 1024};  // fself rows 1024..2047
        ap.d[1] = ADesc{q2, k2, vt2, fo2, 2048, 512, 768, 0};      // fcross
        GPack p; p.n = 1; int te = 0;
        gl(p, 0, sbufS, 512, wqkvT_sc + 512 * 512, 512, scross_bqkv + 512, kcs, 512,
           1024, 1024, 512, 4, 0, vtcs, 9, 64, te);                // scross kv
        hipLaunchKernelGGL(fat_multi<4>, dim3(768 + te), dim3(256), 0, stream,
                           ap, p, w_null, cv_null, 768, te, 0, PRESCALE);
    }

    // ---- L4: scross-attn || out-proj {fself, fcross, sself} (TM=64) ----
    {
        APack ap; ap.n = 1;
        ap.d[0] = ADesc{qcs, kcs, vtcs, so2, 512, 512, 128, 0};    // scross
        GPack p; p.n = 3; int te = 0;
        gl(p, 0, fo1, 512, woT_f, 512, fself_bo, zf, 1024,
           4096, 512, 512, 0, 0, 0, 0, 64, te);
        gl(p, 1, fo2, 512, woT_c, 512, fcross_bo, zf + 512, 1024,
           4096, 512, 512, 0, 0, 0, 0, 64, te);
        gl(p, 2, so1, 512, woT_s, 512, sself_bo, zs, 1024,
           1024, 512, 512, 0, 0, 0, 0, 64, te);
        hipLaunchKernelGGL(fat_multi<4>, dim3(128 + te), dim3(256), 0, stream,
                           ap, p, w_null, cv_null, 128, te, 0, PRESCALE);
    }

    // ---- L5: out-proj scross (TM=64) ----
    {
        GPack p; p.n = 1; int te = 0;
        gl(p, 0, so2, 512, woT_sc, 512, scross_bo, zs + 512, 1024,
           1024, 512, 512, 0, 0, 0, 0, 64, te);
        hipLaunchKernelGGL(fat_multi<4>, dim3(te), dim3(256), 0, stream,
                           a_null, p, w_null, cv_null, 0, te, 0, PRESCALE);
    }
}